// Round 5
// baseline (78869.275 us; speedup 1.0000x reference)
//
#include <hip/hip_runtime.h>
#include <stdint.h>

// ---------------------------------------------------------------------------
// BioDecoder: 64-step LSTM decoder w/ attention, rep-penalty, temperature=0.4,
// top-p=0.7, jax.random.categorical (Threefry partitionable). All fp32.
// Association discipline: every dot = strict sequential-k single-acc fma chain.
// R7: PERSISTENT whole-decode kernel. Evidence (R2->R4: GEMM overhaul moved
// total by only 8.6us/step; R6: sampler fix 17us/step) says ~300us/step is
// inter-kernel launch/drain overhead. One kernel, 256 blocks x 256 thr
// (1 block/CU co-resident), software device-scope grid barrier between
// phases. All phase arithmetic verbatim from R6 (bit-exact associations);
// sampler 1024-thr reductions split 4x256 with exact tree-pairing replicated.
// ---------------------------------------------------------------------------

#define B_   64
#define H_   1024
#define E_   512
#define DV_  512
#define KV_  49
#define V_   32000
#define T_   64
#define NBLK 256

// ------------------------- Threefry-2x32-20 (JAX) --------------------------
__device__ __forceinline__ uint32_t rotl32(uint32_t x, int r) {
  return (x << r) | (x >> (32 - r));
}
__device__ __forceinline__ void tf2x32(uint32_t k0, uint32_t k1,
                                       uint32_t x0, uint32_t x1,
                                       uint32_t& o0, uint32_t& o1) {
  uint32_t ks0 = k0, ks1 = k1, ks2 = k0 ^ k1 ^ 0x1BD11BDAu;
  x0 += ks0; x1 += ks1;
#define RND_(r) { x0 += x1; x1 = rotl32(x1, r) ^ x0; }
  RND_(13) RND_(15) RND_(26) RND_(6)  x0 += ks1; x1 += ks2 + 1u;
  RND_(17) RND_(29) RND_(16) RND_(24) x0 += ks2; x1 += ks0 + 2u;
  RND_(13) RND_(15) RND_(26) RND_(6)  x0 += ks0; x1 += ks1 + 3u;
  RND_(17) RND_(29) RND_(16) RND_(24) x0 += ks1; x1 += ks2 + 4u;
  RND_(13) RND_(15) RND_(26) RND_(6)  x0 += ks2; x1 += ks0 + 5u;
#undef RND_
  o0 = x0; o1 = x1;
}

__device__ __forceinline__ unsigned key_of(float f) {
  unsigned u = __float_as_uint(f);
  return (u & 0x80000000u) ? ~u : (u | 0x80000000u);
}
__device__ __forceinline__ float sigf(float x) { return 1.0f / (1.0f + expf(-x)); }

// ------------------------- software grid barrier ---------------------------
// Sense-reversing, device(agent)-scope. bar[0]=count, bar[1]=generation.
// Co-residency: 256 blocks x 256 thr, 55KB LDS -> 1 block/CU on 256 CUs.
__device__ __forceinline__ void gsync(unsigned* bar) {
  __syncthreads();
  if (threadIdx.x == 0) {
    __threadfence();  // publish this block's writes (agent scope, L2 wb)
    unsigned g = __hip_atomic_load(&bar[1], __ATOMIC_RELAXED, __HIP_MEMORY_SCOPE_AGENT);
    unsigned a = __hip_atomic_fetch_add(&bar[0], 1u, __ATOMIC_ACQ_REL, __HIP_MEMORY_SCOPE_AGENT);
    if (a + 1u == (unsigned)NBLK) {
      __hip_atomic_store(&bar[0], 0u, __ATOMIC_RELAXED, __HIP_MEMORY_SCOPE_AGENT);
      __hip_atomic_store(&bar[1], g + 1u, __ATOMIC_RELEASE, __HIP_MEMORY_SCOPE_AGENT);
    } else {
      while (__hip_atomic_load(&bar[1], __ATOMIC_ACQUIRE, __HIP_MEMORY_SCOPE_AGENT) == g)
        __builtin_amdgcn_s_sleep(2);
    }
  }
  __syncthreads();
}

__global__ void bar_init(unsigned* bar) {
  if (threadIdx.x < 2) bar[threadIdx.x] = 0u;
}

// ------------------------- device GEMM tile --------------------------------
// Verbatim math from R6 gemm_dq: out[m][n] = sum_k A[m][k]*W[n][k], k ascending,
// one fma chain per output. XOR-swizzled LDS, reg-prefetch double buffer.
// act-guard lets a 256-thr block run a 128-thr tile (idle threads still hit
// the block barriers). Sb0 = LDS base (float*), holds 2*(64+BN)*36 floats.
template <int BN, int TM, int TN, int NTHR>
__device__ void gemm_tile(int tid, float* Sb0, int n0, int m0,
                          const float* __restrict__ A, int lda,
                          const float* __restrict__ W, int ldw, int K,
                          float* __restrict__ out, int ldo) {
  constexpr int LD = 36;
  constexpr int ROWS = 64 + BN;
  constexpr int NF4 = ROWS * 8 / NTHR;
  constexpr int BUFST = ROWS * LD;
  constexpr int CG = BN / TN;
  static_assert(ROWS * 8 % NTHR == 0, "staging divisibility");
  static_assert((64 / TM) * CG == NTHR, "thread grid");
  static_assert(TN == 4, "float4 epilogue");
  const bool act = tid < NTHR;
  const int tc = tid % CG, tr = tid / CG;
  const float* gp[NF4];
  float* lp[NF4];
  float4 pre[NF4];
  if (act) {
#pragma unroll
    for (int q = 0; q < NF4; ++q) {
      int l = tid + q * NTHR;
      int r = l >> 3, c4 = l & 7;
      gp[q] = (l < 512) ? (A + (m0 + r) * lda + c4 * 4)
                        : (W + (n0 + (r - 64)) * ldw + c4 * 4);
      lp[q] = Sb0 + r * LD + ((c4 ^ ((r >> 2) & 7)) << 2);
    }
#pragma unroll
    for (int q = 0; q < NF4; ++q) pre[q] = *(const float4*)gp[q];
#pragma unroll
    for (int q = 0; q < NF4; ++q) *(float4*)lp[q] = pre[q];
  }
  __syncthreads();
  float acc[TM][TN] = {};
  const int nch = K >> 5;
  for (int c = 0; c < nch; ++c) {
    const bool more = (c + 1 < nch);
    if (act && more) {
      const int kc = (c + 1) << 5;
#pragma unroll
      for (int q = 0; q < NF4; ++q) pre[q] = *(const float4*)(gp[q] + kc);
    }
    if (act) {
      const float* Sb = Sb0 + (c & 1) * BUFST;
#pragma unroll
      for (int kk = 0; kk < 8; ++kk) {
        float4 a4[TM], w4[TN];
#pragma unroll
        for (int i = 0; i < TM; ++i) {
          int m = tr * TM + i;
          a4[i] = *(const float4*)(Sb + m * LD + ((kk ^ ((m >> 2) & 7)) << 2));
        }
#pragma unroll
        for (int j = 0; j < TN; ++j) {
          int rw = 64 + tc * TN + j;
          w4[j] = *(const float4*)(Sb + rw * LD + ((kk ^ ((rw >> 2) & 7)) << 2));
        }
#pragma unroll
        for (int i = 0; i < TM; ++i)
#pragma unroll
          for (int j = 0; j < TN; ++j) {
            acc[i][j] = fmaf(a4[i].x, w4[j].x, acc[i][j]);
            acc[i][j] = fmaf(a4[i].y, w4[j].y, acc[i][j]);
            acc[i][j] = fmaf(a4[i].z, w4[j].z, acc[i][j]);
            acc[i][j] = fmaf(a4[i].w, w4[j].w, acc[i][j]);
          }
      }
    }
    if (act && more) {
      const int bo2 = ((c + 1) & 1) * BUFST;
#pragma unroll
      for (int q = 0; q < NF4; ++q) *(float4*)(lp[q] + bo2) = pre[q];
    }
    __syncthreads();
  }
  if (act) {
#pragma unroll
    for (int i = 0; i < TM; ++i) {
      float4 o;
      o.x = acc[i][0]; o.y = acc[i][1]; o.z = acc[i][2]; o.w = acc[i][3];
      *(float4*)&out[(m0 + tr * TM + i) * ldo + n0 + tc * TN] = o;
    }
  }
}

// ------------------------- LDS overlays ------------------------------------
struct LnLds   { float buf[H_]; float red[256]; };
struct AttnLds { float t1[H_]; float outv[H_]; float attn[64]; float gate; };
struct SamLds  {
  float redf[256]; int redi[256];
  unsigned long long whist[4][257];
  unsigned long long suf[256];
  unsigned long long wq[4];
  unsigned long long carry;
  unsigned prefix;
  int jstar;
};

// ------------------------- param pack --------------------------------------
struct MegaP {
  const float *thought, *visf, *embedding;
  const float *Wih1, *Whh1, *bih1, *bhh1;
  const float *Wih2, *Whh2, *bih2, *bhh2;
  const float *Wg1, *bg1, *Wg2, *bg2;
  const float *Wo, *bo, *Wv, *bv, *ln_g, *ln_b;
  float *vp, *xcat1, *xcat2, *c1, *c2, *h2buf, *ctx, *dx, *dh, *dg, *dlog, *Lb, *Eb;
  int *hist, *histv, *outTok;
  float *pM, *pS, *pGv;
  int *pGi;
  unsigned long long *pH;
  unsigned *bar;
};

// ------------------------- the persistent kernel ---------------------------
__global__ __launch_bounds__(256, 1)
void mega(MegaP p) {
  __shared__ __align__(16) unsigned char LDSU_[55296];  // 2*(64+128)*36*4
  float* GS = (float*)LDSU_;
  const int bx = blockIdx.x;
  const int tid = threadIdx.x;

  // ---- P0: init_state (verbatim) + visual_proj GEMM ----
  {
    int i = bx * 256 + tid;
    if (i < B_ * H_) {
      int b = i >> 10, h = i & 1023;
      p.c1[i] = 0.f; p.c2[i] = 0.f;
      float th = p.thought[i];
      p.xcat1[b * (E_ + H_) + E_ + h] = th;
      p.xcat2[b * (2 * H_) + H_ + h] = th;
      if (h < E_) p.xcat1[b * (E_ + H_) + h] = p.embedding[E_ + h];
    }
    if (i < B_ * 3) { p.hist[i] = 0; p.histv[i] = 0; }
  }
  for (int s = bx; s < 8 * KV_; s += NBLK)
    gemm_tile<128, 8, 4, 256>(tid, GS, (s & 7) * 128, (s >> 3) * 64,
                              p.visf, DV_, p.Wv, DV_, DV_, p.vp, H_);
  gsync(p.bar);

  // ---- P1: LayerNorm over 3136 rows (verbatim body + trailing barrier) ----
  for (int row = bx; row < B_ * KV_; row += NBLK) {
    LnLds& LL = *(LnLds*)LDSU_;
    float* pp = p.vp + (long long)row * H_;
    for (int h = tid; h < H_; h += 256) LL.buf[h] = __fadd_rn(pp[h], p.bv[h]);
    __syncthreads();
    float s = 0;
    for (int h = tid; h < H_; h += 256) s += LL.buf[h];
    LL.red[tid] = s; __syncthreads();
    for (int off = 128; off > 0; off >>= 1) { if (tid < off) LL.red[tid] += LL.red[tid + off]; __syncthreads(); }
    float mu = LL.red[0] / (float)H_;
    __syncthreads();
    float vs = 0;
    for (int h = tid; h < H_; h += 256) { float d = LL.buf[h] - mu; vs += d * d; }
    LL.red[tid] = vs; __syncthreads();
    for (int off = 128; off > 0; off >>= 1) { if (tid < off) LL.red[tid] += LL.red[tid + off]; __syncthreads(); }
    float var = LL.red[0] / (float)H_;
    float sq = sqrtf(var + 1e-5f);
    for (int h = tid; h < H_; h += 256) {
      float nrm = __fdiv_rn(__fsub_rn(LL.buf[h], mu), sq);
      pp[h] = __fadd_rn(__fmul_rn(nrm, p.ln_g[h]), p.ln_b[h]);
    }
    __syncthreads();   // buf reuse across rows
  }
  gsync(p.bar);

  // ---- decode loop ----
  for (int t = 0; t < T_; ++t) {
    // L1 GEMM: dx = emb @ Wih1^T (K=512) | dh = h1 @ Whh1^T (K=1024)
    if (bx < 128)
      gemm_tile<32, 4, 4, 128>(tid, GS, bx * 32, 0,
                               p.xcat1, E_ + H_, p.Wih1, E_, E_, p.dx, 4096);
    else
      gemm_tile<32, 4, 4, 128>(tid, GS, (bx - 128) * 32, 0,
                               p.xcat1 + E_, E_ + H_, p.Whh1, H_, H_, p.dh, 4096);
    gsync(p.bar);
    // lstm1 (verbatim)
    {
      int idx = bx * 256 + tid;
      int b = idx >> 10, h = idx & 1023;
      float z[4];
#pragma unroll
      for (int g = 0; g < 4; g++) {
        int j = g * 1024 + h;
        float s = __fadd_rn(p.dx[b * 4096 + j], p.dh[b * 4096 + j]);
        s = __fadd_rn(s, p.bih1[j]);
        s = __fadd_rn(s, p.bhh1[j]);
        z[g] = s;
      }
      float fc = __fmul_rn(sigf(z[1]), p.c1[idx]);
      float ig = __fmul_rn(sigf(z[0]), tanhf(z[2]));
      float cn = __fadd_rn(fc, ig);
      float hn = __fmul_rn(sigf(z[3]), tanhf(cn));
      p.c1[idx] = cn;
      p.xcat1[(long long)b * (E_ + H_) + E_ + h] = hn;
      p.xcat2[(long long)b * (2 * H_) + h] = hn;
    }
    gsync(p.bar);
    // L2 GEMM
    if (bx < 128)
      gemm_tile<32, 4, 4, 128>(tid, GS, bx * 32, 0,
                               p.xcat2, 2 * H_, p.Wih2, H_, H_, p.dx, 4096);
    else
      gemm_tile<32, 4, 4, 128>(tid, GS, (bx - 128) * 32, 0,
                               p.xcat2 + H_, 2 * H_, p.Whh2, H_, H_, p.dh, 4096);
    gsync(p.bar);
    // lstm2 (verbatim)
    {
      int idx = bx * 256 + tid;
      int b = idx >> 10, h = idx & 1023;
      float z[4];
#pragma unroll
      for (int g = 0; g < 4; g++) {
        int j = g * 1024 + h;
        float s = __fadd_rn(p.dx[b * 4096 + j], p.dh[b * 4096 + j]);
        s = __fadd_rn(s, p.bih2[j]);
        s = __fadd_rn(s, p.bhh2[j]);
        z[g] = s;
      }
      float fc = __fmul_rn(sigf(z[1]), p.c2[idx]);
      float ig = __fmul_rn(sigf(z[0]), tanhf(z[2]));
      float cn = __fadd_rn(fc, ig);
      float hn = __fmul_rn(sigf(z[3]), tanhf(cn));
      p.c2[idx] = cn;
      p.h2buf[(long long)b * H_ + h] = hn;
      p.xcat2[(long long)b * (2 * H_) + H_ + h] = hn;
    }
    gsync(p.bar);
    // gate GEMM: dg = h2 @ Wg1^T (32 tiles)
    if (bx < 32)
      gemm_tile<32, 4, 4, 128>(tid, GS, bx * 32, 0,
                               p.h2buf, H_, p.Wg1, H_, H_, p.dg, H_);
    gsync(p.bar);
    // gate + attention (verbatim body)
    if (bx < B_) {
      AttnLds& AL = *(AttnLds*)LDSU_;
      int b = bx;
      for (int h = tid; h < H_; h += 256)
        AL.t1[h] = tanhf(__fadd_rn(p.dg[b * H_ + h], p.bg1[h]));
      __syncthreads();
      if (tid == 0) {
        float s = 0;
        for (int h = 0; h < H_; h++) s = fmaf(AL.t1[h], p.Wg2[h], s);
        AL.gate = sigf(__fadd_rn(s, p.bg2[0]));
      }
      __syncthreads();
      float gate = AL.gate;
      for (int h = tid; h < H_; h += 256) AL.outv[h] = __fmul_rn(p.h2buf[b * H_ + h], gate);
      __syncthreads();
      if (tid < KV_) {
        const float* vrow = p.vp + ((long long)b * KV_ + tid) * H_;
        float a = 0;
        for (int h = 0; h < H_; h++) a = fmaf(AL.outv[h], vrow[h], a);
        AL.attn[tid] = __fmul_rn(a, 0.03125f);
      }
      __syncthreads();
      if (tid == 0) {
        float m = -INFINITY;
        for (int k = 0; k < KV_; k++) m = fmaxf(m, AL.attn[k]);
        float ss = 0;
        for (int k = 0; k < KV_; k++) { AL.attn[k] = expf(AL.attn[k] - m); ss += AL.attn[k]; }
        for (int k = 0; k < KV_; k++) AL.attn[k] = __fdiv_rn(AL.attn[k], ss);
      }
      __syncthreads();
      for (int h = tid; h < H_; h += 256) {
        float acc = 0;
        for (int k = 0; k < KV_; k++) acc = fmaf(AL.attn[k], p.vp[((long long)b * KV_ + k) * H_ + h], acc);
        p.ctx[b * H_ + h] = __fadd_rn(AL.outv[h], acc);
      }
    }
    gsync(p.bar);
    // logits GEMM: dlog = ctx @ Wo^T (250 tiles of BN=128)
    if (bx < 250)
      gemm_tile<128, 8, 4, 256>(tid, GS, bx * 128, 0,
                                p.ctx, H_, p.Wo, H_, H_, p.dlog, V_);
    gsync(p.bar);

    // ---- sampler: 4 role-blocks per batch b, exact R6 math ----
    {
      const int b = bx >> 2, role = bx & 3;
      const int gtid = (role << 8) | tid;      // == old tid within 1024-thr block
      SamLds& SL = *(SamLds*)LDSU_;
      int hh0 = p.hist[b * 3 + 0], hh1 = p.hist[b * 3 + 1], hh2 = p.hist[b * 3 + 2];
      int q0 = p.histv[b * 3 + 0] ? hh0 : -1;
      int q1 = p.histv[b * 3 + 1] ? hh1 : -1;
      int q2 = p.histv[b * 3 + 2] ? hh2 : -1;
      const float* pa = p.dlog + (long long)b * V_;
      float* L = p.Lb + (long long)b * V_;
      float* E = p.Eb + (long long)b * V_;

      // pass 1: scaled logits + max
      float lm = -INFINITY;
      for (int v = gtid; v < V_; v += 1024) {
        float raw = __fadd_rn(pa[v], p.bo[v]);
        if (v == q0 || v == q1 || v == q2) raw = __fsub_rn(raw, 2.0f);
        float l = __fdiv_rn(raw, 0.4f);
        L[v] = l;
        lm = fmaxf(lm, l);
      }
      p.pM[(b * 4 + role) * 256 + tid] = lm;
      gsync(p.bar);
      {
        const float* s0 = p.pM + (b * 4 + 0) * 256;
        const float* s1 = p.pM + (b * 4 + 1) * 256;
        const float* s2 = p.pM + (b * 4 + 2) * 256;
        const float* s3 = p.pM + (b * 4 + 3) * 256;
        // exact 1024-tree pairing: step512 = (s0,s2),(s1,s3); step256 combines
        SL.redf[tid] = fmaxf(fmaxf(s0[tid], s2[tid]), fmaxf(s1[tid], s3[tid]));
      }
      __syncthreads();
      for (int off = 128; off > 0; off >>= 1) { if (tid < off) SL.redf[tid] = fmaxf(SL.redf[tid], SL.redf[tid + off]); __syncthreads(); }
      float m = SL.redf[0];
      __syncthreads();

      // pass 2: exp + sum
      float ls = 0;
      for (int v = gtid; v < V_; v += 1024) { float e = expf(L[v] - m); E[v] = e; ls += e; }
      p.pS[(b * 4 + role) * 256 + tid] = ls;
      gsync(p.bar);
      {
        const float* s0 = p.pS + (b * 4 + 0) * 256;
        const float* s1 = p.pS + (b * 4 + 1) * 256;
        const float* s2 = p.pS + (b * 4 + 2) * 256;
        const float* s3 = p.pS + (b * 4 + 3) * 256;
        SL.redf[tid] = (s0[tid] + s2[tid]) + (s1[tid] + s3[tid]);
      }
      __syncthreads();
      for (int off = 128; off > 0; off >>= 1) { if (tid < off) SL.redf[tid] += SL.redf[tid + off]; __syncthreads(); }
      float Z = SL.redf[0];
      __syncthreads();

      // radix select (integer, order-independent)
      const double SC = 17592186044416.0; // 2^44
      const unsigned long long B0 =
          (unsigned long long)(0.699999988079071044921875 * 17592186044416.0);
      if (tid == 0) { SL.carry = 0ull; SL.prefix = 0u; }
      __syncthreads();
      for (int pass = 0; pass < 4; pass++) {
        int shift = 24 - 8 * pass;
        unsigned maskk = (pass == 0) ? 0u : (0xFFFFFFFFu << (shift + 8));
        for (int i = tid; i < 4 * 257; i += 256) ((unsigned long long*)SL.whist)[i] = 0ull;
        __syncthreads();
        unsigned pref = SL.prefix;
        unsigned long long carry = SL.carry;
        for (int v = gtid; v < V_; v += 1024) {
          unsigned key = key_of(L[v]);
          if ((key & maskk) == pref) {
            unsigned bin = (key >> shift) & 255u;
            unsigned long long S = (unsigned long long)((double)(E[v] / Z) * SC);
            atomicAdd(&SL.whist[tid >> 6][bin], (S << 16) | 1ull);
          }
        }
        __syncthreads();
        {
          unsigned long long part =
              ((SL.whist[0][tid] + SL.whist[1][tid]) + SL.whist[2][tid]) + SL.whist[3][tid];
          p.pH[((pass * B_ + b) * 4 + role) * 256 + tid] = part;
        }
        gsync(p.bar);
        unsigned long long bs =
            ((p.pH[((pass * B_ + b) * 4 + 0) * 256 + tid] +
              p.pH[((pass * B_ + b) * 4 + 1) * 256 + tid]) +
             p.pH[((pass * B_ + b) * 4 + 2) * 256 + tid]) +
            p.pH[((pass * B_ + b) * 4 + 3) * 256 + tid];
        if (tid == 0) SL.jstar = 256;
        __syncthreads();
        unsigned long long sown = bs >> 16;
        unsigned long long sincl = sown;
#pragma unroll
        for (int off = 1; off < 64; off <<= 1) {
          unsigned long long o = __shfl_down(sincl, off);
          if ((tid & 63) + off < 64) sincl += o;
        }
        if ((tid & 63) == 0) SL.wq[tid >> 6] = sincl;
        __syncthreads();
        {
          unsigned long long add = 0ull;
          for (int w2 = (tid >> 6) + 1; w2 < 4; ++w2) add += SL.wq[w2];
          SL.suf[tid] = sincl + add - sown;
        }
        __syncthreads();
        if ((unsigned)(bs & 0xFFFFull) > 0u) {
          unsigned long long A = carry + SL.suf[tid];
          if (A <= B0) atomicMin(&SL.jstar, tid);
        }
        __syncthreads();
        if (tid == 0) {
          int j = SL.jstar;
          SL.carry = carry + SL.suf[j];
          SL.prefix = pref | (((unsigned)j) << shift);
        }
        __syncthreads();
      }
      unsigned Kstar = SL.prefix;

      // step key
      unsigned kt0, kt1;
      tf2x32(0u, 42u, 0u, (unsigned)t, kt0, kt1);

      // gumbel argmax over kept set
      float bestv = -INFINITY; int besti = 0x7fffffff;
      for (int v = gtid; v < V_; v += 1024) {
        float l = L[v];
        if (key_of(l) >= Kstar) {
          unsigned r0, r1;
          tf2x32(kt0, kt1, 0u, (unsigned)(b * V_ + v), r0, r1);
          unsigned bits = r0 ^ r1;
          float u = __uint_as_float((bits >> 9) | 0x3f800000u) - 1.0f;
          u = fmaxf(u, 1.17549435e-38f);
          float gum = -logf(-logf(u));
          float val = __fadd_rn(l, gum);
          if (val > bestv) { bestv = val; besti = v; }
        }
      }
      p.pGv[(b * 4 + role) * 256 + tid] = bestv;
      p.pGi[(b * 4 + role) * 256 + tid] = besti;
      gsync(p.bar);
      {
        const float* v0 = p.pGv + (b * 4 + 0) * 256;
        const float* v1 = p.pGv + (b * 4 + 1) * 256;
        const float* v2 = p.pGv + (b * 4 + 2) * 256;
        const float* v3 = p.pGv + (b * 4 + 3) * 256;
        const int* i0 = p.pGi + (b * 4 + 0) * 256;
        const int* i1 = p.pGi + (b * 4 + 1) * 256;
        const int* i2 = p.pGi + (b * 4 + 2) * 256;
        const int* i3 = p.pGi + (b * 4 + 3) * 256;
        float av = v0[tid]; int ai = i0[tid];
        float ov = v2[tid]; int oi = i2[tid];
        if (ov > av || (ov == av && oi < ai)) { av = ov; ai = oi; }
        float bv = v1[tid]; int bi = i1[tid];
        ov = v3[tid]; oi = i3[tid];
        if (ov > bv || (ov == bv && oi < bi)) { bv = ov; bi = oi; }
        if (bv > av || (bv == av && bi < ai)) { av = bv; ai = bi; }
        SL.redf[tid] = av; SL.redi[tid] = ai;
      }
      __syncthreads();
      for (int off = 128; off > 0; off >>= 1) {
        if (tid < off) {
          float ov = SL.redf[tid + off]; int oi = SL.redi[tid + off];
          if (ov > SL.redf[tid] || (ov == SL.redf[tid] && oi < SL.redi[tid])) { SL.redf[tid] = ov; SL.redi[tid] = oi; }
        }
        __syncthreads();
      }
      int tok = SL.redi[0];
      if (role == 0 && tid == 0) {
        p.outTok[b * T_ + t] = tok;
        p.hist[b * 3 + 0] = hh1; p.hist[b * 3 + 1] = hh2; p.hist[b * 3 + 2] = tok;
        int v1h = p.histv[b * 3 + 1], v2h = p.histv[b * 3 + 2];
        p.histv[b * 3 + 0] = v1h; p.histv[b * 3 + 1] = v2h; p.histv[b * 3 + 2] = 1;
      }
      if (gtid < E_)
        p.xcat1[b * (E_ + H_) + gtid] = p.embedding[(long long)tok * E_ + gtid];
    }
    gsync(p.bar);   // step end: xcat1/hist published for next step
  }
}

// ---------------------------------------------------------------------------
extern "C" void kernel_launch(void* const* d_in, const int* in_sizes, int n_in,
                              void* d_out, int out_size, void* d_ws, size_t ws_size,
                              hipStream_t stream) {
  MegaP p;
  p.thought   = (const float*)d_in[0];
  p.visf      = (const float*)d_in[1];
  p.embedding = (const float*)d_in[3];
  p.Wih1 = (const float*)d_in[4];
  p.Whh1 = (const float*)d_in[5];
  p.bih1 = (const float*)d_in[6];
  p.bhh1 = (const float*)d_in[7];
  p.Wih2 = (const float*)d_in[8];
  p.Whh2 = (const float*)d_in[9];
  p.bih2 = (const float*)d_in[10];
  p.bhh2 = (const float*)d_in[11];
  p.Wg1  = (const float*)d_in[12];
  p.bg1  = (const float*)d_in[13];
  p.Wg2  = (const float*)d_in[14];
  p.bg2  = (const float*)d_in[15];
  p.Wo   = (const float*)d_in[16];
  p.bo   = (const float*)d_in[17];
  p.Wv   = (const float*)d_in[18];
  p.bv   = (const float*)d_in[19];
  p.ln_g = (const float*)d_in[20];
  p.ln_b = (const float*)d_in[21];
  p.outTok = (int*)d_out;

  float* ws = (float*)d_ws;
  long long off = 0;
  p.vp    = ws + off; off += (long long)B_ * KV_ * H_;
  p.xcat1 = ws + off; off += B_ * (E_ + H_);
  p.xcat2 = ws + off; off += B_ * (2 * H_);
  p.c1    = ws + off; off += B_ * H_;
  p.c2    = ws + off; off += B_ * H_;
  p.h2buf = ws + off; off += B_ * H_;
  p.ctx   = ws + off; off += B_ * H_;
  p.dx    = ws + off; off += (long long)B_ * 4096;
  p.dh    = ws + off; off += (long long)B_ * 4096;
  p.dg    = ws + off; off += (long long)B_ * H_;
  p.dlog  = ws + off; off += (long long)B_ * V_;
  p.Lb    = ws + off; off += (long long)B_ * V_;
  p.Eb    = ws + off; off += (long long)B_ * V_;
  p.hist  = (int*)(ws + off); off += 256;
  p.histv = (int*)(ws + off); off += 256;
  p.pM    = ws + off; off += B_ * 4 * 256;
  p.pS    = ws + off; off += B_ * 4 * 256;
  p.pGv   = ws + off; off += B_ * 4 * 256;
  p.pGi   = (int*)(ws + off); off += B_ * 4 * 256;
  p.pH    = (unsigned long long*)(ws + off); off += (long long)4 * B_ * 4 * 256 * 2;  // u64
  p.bar   = (unsigned*)(ws + off); off += 64;

  bar_init<<<1, 64, 0, stream>>>(p.bar);
  mega<<<NBLK, 256, 0, stream>>>(p);
}